// Round 10
// baseline (165.631 us; speedup 1.0000x reference)
//
#include <hip/hip_runtime.h>
#include <hip/hip_bf16.h>
#include <stdint.h>

#define TT 16384
#define DD 768
#define EE 8
#define FF 469
#define FP 512
#define NCHUNK (TT / 64)
#define MAXTILES 136

typedef __attribute__((ext_vector_type(8))) short s16x8;
typedef __attribute__((ext_vector_type(4))) float f32x4;

__device__ __forceinline__ ushort f2bf(float f) {
  uint32_t u = __builtin_bit_cast(uint32_t, f);
  u += 0x7fffu + ((u >> 16) & 1u);
  return (ushort)(u >> 16);
}

__device__ __forceinline__ void gload16(const void* g, void* l) {
  __builtin_amdgcn_global_load_lds((const __attribute__((address_space(1))) unsigned int*)g,
                                   (__attribute__((address_space(3))) unsigned int*)l,
                                   16, 0, 0);
}

// ---------------- fused gating (fp32) + x->bf16 conversion + chunk histogram ----------------
__global__ __launch_bounds__(256) void gate_conv_kernel(
    const float* __restrict__ x, const float* __restrict__ Wg,
    const float* __restrict__ bg, int* __restrict__ eidx,
    ushort* __restrict__ xbf, int* __restrict__ cnt) {
  __shared__ float4 wgs[EE * DD / 4];  // 24 KB
  int tid = threadIdx.x;
  for (int i = tid; i < EE * DD / 4; i += 256) wgs[i] = ((const float4*)Wg)[i];
  __syncthreads();

  int t = blockIdx.x * 4 + (tid >> 6);
  int lane = tid & 63;
  const float4* xr = (const float4*)(x + (size_t)t * DD);
  float4 xv[3];
#pragma unroll
  for (int k = 0; k < 3; ++k) xv[k] = xr[lane + 64 * k];

  float acc[EE];
#pragma unroll
  for (int e = 0; e < EE; ++e) acc[e] = 0.f;
#pragma unroll
  for (int k = 0; k < 3; ++k) {
#pragma unroll
    for (int e = 0; e < EE; ++e) {
      float4 w = wgs[e * 192 + lane + 64 * k];
      acc[e] += xv[k].x * w.x + xv[k].y * w.y + xv[k].z * w.z + xv[k].w * w.w;
    }
  }

  uint2* xd = (uint2*)(xbf + (size_t)t * DD);
#pragma unroll
  for (int k = 0; k < 3; ++k) {
    union { ushort u[4]; uint2 w; } p;
    p.u[0] = f2bf(xv[k].x); p.u[1] = f2bf(xv[k].y);
    p.u[2] = f2bf(xv[k].z); p.u[3] = f2bf(xv[k].w);
    xd[lane + 64 * k] = p.w;
  }

#pragma unroll
  for (int off = 32; off; off >>= 1) {
#pragma unroll
    for (int e = 0; e < EE; ++e) acc[e] += __shfl_down(acc[e], off);
  }
  if (lane == 0) {
    float best = acc[0] + bg[0];
    int bi = 0;
#pragma unroll
    for (int e = 1; e < EE; ++e) {
      float v = acc[e] + bg[e];
      if (v > best) { best = v; bi = e; }
    }
    eidx[t] = bi;
    atomicAdd(&cnt[bi * NCHUNK + (t >> 6)], 1);  // 2048 counters, <=64 adds each
  }
}

// ---------------- wave-parallel exclusive scan + flat tile table ----------------
__global__ void scan_kernel(const int* __restrict__ cnt, int* __restrict__ scanEx,
                            int* __restrict__ offs, int* __restrict__ tileE,
                            int* __restrict__ tileT0) {
  int e = threadIdx.x >> 6;
  int lane = threadIdx.x & 63;
  __shared__ int totals[EE];
  int carry = 0;
#pragma unroll
  for (int g = 0; g < NCHUNK / 64; ++g) {
    int v = cnt[e * NCHUNK + g * 64 + lane];
    int s = v;
#pragma unroll
    for (int d = 1; d < 64; d <<= 1) {
      int t = __shfl_up(s, d);
      if (lane >= d) s += t;
    }
    scanEx[e * NCHUNK + g * 64 + lane] = carry + s - v;
    carry += __shfl(s, 63);
  }
  if (lane == 0) totals[e] = carry;
  __syncthreads();
  if (threadIdx.x == 0) {
    int s = 0;
    for (int e2 = 0; e2 < EE; ++e2) { offs[e2] = s; s += totals[e2]; }
    offs[EE] = s;
    int idx = 0;
    for (int e2 = 0; e2 < EE; ++e2) {
      int nt = (totals[e2] + 127) >> 7;
      for (int j = 0; j < nt; ++j) { tileE[idx] = e2; tileT0[idx] = j << 7; ++idx; }
    }
    for (; idx < MAXTILES; ++idx) tileE[idx] = -1;
  }
}

// ---------------- scatter via in-chunk ballot rank ----------------
__global__ void scatter2_kernel(const int* __restrict__ eidx, const int* __restrict__ offs,
                                const int* __restrict__ scanEx, int* __restrict__ perm) {
  int c = blockIdx.x * 4 + (threadIdx.x >> 6);
  int lane = threadIdx.x & 63;
  int t = c * 64 + lane;
  int v = eidx[t];
  unsigned long long mym = 0;
#pragma unroll
  for (int e = 0; e < EE; ++e) {
    unsigned long long me = __ballot(v == e);
    if (v == e) mym = me;
  }
  int rank = __popcll(mym & ((1ULL << lane) - 1ULL));
  perm[offs[v] + scanEx[v * NCHUNK + c] + rank] = t;
}

// ---------------- merged weight conversions: w12b (interleaved) + w3b (padded) ----------------
#define N12 (EE * 2 * FP * (DD / 4))
#define N3  (EE * DD * (FP / 4))
__global__ void convw_kernel(const float* __restrict__ W1, const float* __restrict__ W2,
                             const float* __restrict__ W3, ushort* __restrict__ w12b,
                             ushort* __restrict__ w3b) {
  for (int i = blockIdx.x * blockDim.x + threadIdx.x; i < N12 + N3;
       i += gridDim.x * blockDim.x) {
    if (i < N12) {
      int d4 = i % (DD / 4);
      int er = i / (DD / 4);
      int row = er & 1023;
      int e = er >> 10;
      int f = row >> 1;
      union { ushort u[4]; uint2 w; } p;
      if (f < FF) {
        const float* src = ((row & 1) ? W2 : W1) + ((size_t)e * FF + f) * DD;
        float4 v = ((const float4*)src)[d4];
        p.u[0] = f2bf(v.x); p.u[1] = f2bf(v.y); p.u[2] = f2bf(v.z); p.u[3] = f2bf(v.w);
      } else {
        p.w.x = 0u; p.w.y = 0u;
      }
      ((uint2*)w12b)[i] = p.w;
    } else {
      int j = i - N12;
      int f4 = (j % (FP / 4)) * 4;
      int ed = j / (FP / 4);  // e*DD + d
      union { ushort u[4]; uint2 w; } p;
#pragma unroll
      for (int q = 0; q < 4; ++q) {
        int f = f4 + q;
        p.u[q] = (f < FF) ? f2bf(W3[(size_t)ed * FF + f]) : (ushort)0;
      }
      ((uint2*)w3b)[(size_t)ed * (FP / 4) + (f4 >> 2)] = p.w;
    }
  }
}

// ---------------- grouped GEMM1: B-only LDS (3-buf), A direct global->VGPR, counted vmcnt ----------------
__global__ __launch_bounds__(256) void ffn1_kernel(
    const ushort* __restrict__ xbf, const ushort* __restrict__ w12b,
    const int* __restrict__ perm, const int* __restrict__ offs,
    const int* __restrict__ tileE, const int* __restrict__ tileT0,
    ushort* __restrict__ hbf) {
  int bid = blockIdx.x;
  int L = (bid & 7) * MAXTILES + (bid >> 3);
  int ti = L >> 3;
  int y = L & 7;
  int e = tileE[ti];
  if (e < 0) return;
  int tile0 = tileT0[ti];
  int gOff = offs[e];
  int Ne = offs[e + 1] - gOff;
  int n0 = y * 128;

  __shared__ __align__(16) short Bs[3][128 * 32];  // 24 KB, B only

  int tid = threadIdx.x;
  int w = tid >> 6, lane = tid & 63;
  int lr = lane >> 2, lg = lane & 3;

  // B staging (unchanged, proven 0-conflict): wave w stages rows [w*32, w*32+32)
  int r0 = w * 32 + lr, r1 = r0 + 16;
  int g0 = lg ^ ((r0 >> 1) & 3);
  int g1 = lg ^ ((r1 >> 1) & 3);
  const ushort* bsrc0 = w12b + ((size_t)(e << 10) + n0 + r0) * DD + g0 * 8;
  const ushort* bsrc1 = w12b + ((size_t)(e << 10) + n0 + r1) * DD + g1 * 8;
  int sdst0 = (w * 32) * 32;
  int sdst1 = sdst0 + 16 * 32;

  int wr = w >> 1, wc = w & 1;
  int lrow = lane & 15, kh = lane >> 4;
  int boff[4];
#pragma unroll
  for (int n = 0; n < 4; ++n) {
    int rb = wc * 64 + n * 16 + lrow;
    boff[n] = rb * 32 + (kh ^ ((rb >> 1) & 3)) * 8;
  }

  // A direct: per-lane global pointers, 16B at [tok(ra)*DD + k + kh*8]
  int last = gOff + Ne - 1;
  const ushort* aptr[4];
#pragma unroll
  for (int m = 0; m < 4; ++m) {
    int ra = wr * 64 + m * 16 + lrow;
    int tok = perm[min(gOff + tile0 + ra, last)];
    aptr[m] = xbf + (size_t)tok * DD + kh * 8;
  }

  f32x4 acc[4][4];
  f32x4 zero = {0.f, 0.f, 0.f, 0.f};
#pragma unroll
  for (int m = 0; m < 4; ++m)
#pragma unroll
    for (int n = 0; n < 4; ++n) acc[m][n] = zero;

  // prologue: B tiles 0,1 staged; A tile 0 into regs
  gload16(bsrc0, &Bs[0][sdst0]);
  gload16(bsrc1, &Bs[0][sdst1]);
  gload16(bsrc0 + 32, &Bs[1][sdst0]);
  gload16(bsrc1 + 32, &Bs[1][sdst1]);
  s16x8 aC[4], aN[4];
#pragma unroll
  for (int m = 0; m < 4; ++m) aC[m] = *(const s16x8*)aptr[m];

  const int NT = DD / 32;  // 24
#pragma unroll
  for (int t = 0; t < NT; ++t) {
    const int cur = t % 3;
    // newer-than-B(t): B(t+1) x2 + A(t) x4 = 6
    asm volatile("s_waitcnt vmcnt(6)" ::: "memory");
    __builtin_amdgcn_s_barrier();
    __builtin_amdgcn_sched_barrier(0);
    if (t + 2 < NT) {
      int k = (t + 2) * 32;
      gload16(bsrc0 + k, &Bs[(t + 2) % 3][sdst0]);
      gload16(bsrc1 + k, &Bs[(t + 2) % 3][sdst1]);
    }
    if (t + 1 < NT) {
      int k = (t + 1) * 32;
#pragma unroll
      for (int m = 0; m < 4; ++m) aN[m] = *(const s16x8*)(aptr[m] + k);
    }
    s16x8 bfr[4];
#pragma unroll
    for (int n = 0; n < 4; ++n) bfr[n] = *(const s16x8*)&Bs[cur][boff[n]];
    __builtin_amdgcn_s_setprio(1);
#pragma unroll
    for (int m = 0; m < 4; ++m)
#pragma unroll
      for (int n = 0; n < 4; ++n)
        acc[m][n] = __builtin_amdgcn_mfma_f32_16x16x32_bf16(aC[m], bfr[n], acc[m][n], 0, 0, 0);
    __builtin_amdgcn_s_setprio(0);
#pragma unroll
    for (int m = 0; m < 4; ++m) aC[m] = aN[m];
  }

  // epilogue: interleaved cols 2f,2f+1 = u_f,v_f in adjacent lanes (R6-proven)
#pragma unroll
  for (int m = 0; m < 4; ++m) {
    int rbase = tile0 + wr * 64 + m * 16 + kh * 4;
#pragma unroll
    for (int n = 0; n < 4; ++n) {
      int f = (n0 + wc * 64 + n * 16 + lrow) >> 1;
#pragma unroll
      for (int r = 0; r < 4; ++r) {
        float val = acc[m][n][r];
        float par = __shfl_xor(val, 1);
        float u = (lane & 1) ? par : val;
        float vv = (lane & 1) ? val : par;
        float h = (u / (1.f + __expf(-u))) * vv;
        int gr = rbase + r;
        if (!(lane & 1) && gr < Ne)
          hbf[(size_t)(gOff + gr) * FP + f] = f2bf(h);
      }
    }
  }
}

// ---------------- grouped GEMM2: B-only LDS, A direct (contiguous hbf rows) ----------------
__global__ __launch_bounds__(256) void ffn2_kernel(
    const ushort* __restrict__ hbf, const ushort* __restrict__ w3b,
    const int* __restrict__ perm, const int* __restrict__ offs,
    const int* __restrict__ tileE, const int* __restrict__ tileT0,
    float* __restrict__ out) {
  int bid = blockIdx.x;
  int L = (bid & 7) * 102 + (bid >> 3);
  int ti = L / 6;
  int y = L % 6;
  int e = tileE[ti];
  if (e < 0) return;
  int tile0 = tileT0[ti];
  int gOff = offs[e];
  int Ne = offs[e + 1] - gOff;
  int d0 = y * 128;

  __shared__ __align__(16) short Bs[3][128 * 32];

  int tid = threadIdx.x;
  int w = tid >> 6, lane = tid & 63;
  int lr = lane >> 2, lg = lane & 3;

  int r0 = w * 32 + lr, r1 = r0 + 16;
  int g0 = lg ^ ((r0 >> 1) & 3);
  int g1 = lg ^ ((r1 >> 1) & 3);
  const ushort* bsrc0 = w3b + ((size_t)e * DD + d0 + r0) * FP + g0 * 8;
  const ushort* bsrc1 = w3b + ((size_t)e * DD + d0 + r1) * FP + g1 * 8;
  int sdst0 = (w * 32) * 32;
  int sdst1 = sdst0 + 16 * 32;

  int wr = w >> 1, wc = w & 1;
  int lrow = lane & 15, kh = lane >> 4;
  int boff[4];
#pragma unroll
  for (int n = 0; n < 4; ++n) {
    int rb = wc * 64 + n * 16 + lrow;
    boff[n] = rb * 32 + (kh ^ ((rb >> 1) & 3)) * 8;
  }

  int last = gOff + Ne - 1;
  const ushort* aptr[4];
#pragma unroll
  for (int m = 0; m < 4; ++m) {
    int ra = wr * 64 + m * 16 + lrow;
    aptr[m] = hbf + (size_t)min(gOff + tile0 + ra, last) * FP + kh * 8;
  }

  f32x4 acc[4][4];
  f32x4 zero = {0.f, 0.f, 0.f, 0.f};
#pragma unroll
  for (int m = 0; m < 4; ++m)
#pragma unroll
    for (int n = 0; n < 4; ++n) acc[m][n] = zero;

  gload16(bsrc0, &Bs[0][sdst0]);
  gload16(bsrc1, &Bs[0][sdst1]);
  gload16(bsrc0 + 32, &Bs[1][sdst0]);
  gload16(bsrc1 + 32, &Bs[1][sdst1]);
  s16x8 aC[4], aN[4];
#pragma unroll
  for (int m = 0; m < 4; ++m) aC[m] = *(const s16x8*)aptr[m];

  const int NT = FP / 32;  // 16
#pragma unroll
  for (int t = 0; t < NT; ++t) {
    const int cur = t % 3;
    asm volatile("s_waitcnt vmcnt(6)" ::: "memory");
    __builtin_amdgcn_s_barrier();
    __builtin_amdgcn_sched_barrier(0);
    if (t + 2 < NT) {
      int k = (t + 2) * 32;
      gload16(bsrc0 + k, &Bs[(t + 2) % 3][sdst0]);
      gload16(bsrc1 + k, &Bs[(t + 2) % 3][sdst1]);
    }
    if (t + 1 < NT) {
      int k = (t + 1) * 32;
#pragma unroll
      for (int m = 0; m < 4; ++m) aN[m] = *(const s16x8*)(aptr[m] + k);
    }
    s16x8 bfr[4];
#pragma unroll
    for (int n = 0; n < 4; ++n) bfr[n] = *(const s16x8*)&Bs[cur][boff[n]];
    __builtin_amdgcn_s_setprio(1);
#pragma unroll
    for (int m = 0; m < 4; ++m)
#pragma unroll
      for (int n = 0; n < 4; ++n)
        acc[m][n] = __builtin_amdgcn_mfma_f32_16x16x32_bf16(aC[m], bfr[n], acc[m][n], 0, 0, 0);
    __builtin_amdgcn_s_setprio(0);
#pragma unroll
    for (int m = 0; m < 4; ++m) aC[m] = aN[m];
  }

#pragma unroll
  for (int m = 0; m < 4; ++m) {
#pragma unroll
    for (int r = 0; r < 4; ++r) {
      int gr = tile0 + wr * 64 + m * 16 + kh * 4 + r;
      if (gr < Ne) {
        int t = perm[gOff + gr];
        float* orow = out + (size_t)t * DD + d0 + wc * 64;
#pragma unroll
        for (int n = 0; n < 4; ++n) orow[n * 16 + lrow] = acc[m][n][r];
      }
    }
  }
}

extern "C" void kernel_launch(void* const* d_in, const int* in_sizes, int n_in,
                              void* d_out, int out_size, void* d_ws, size_t ws_size,
                              hipStream_t stream) {
  const float* x = (const float*)d_in[0];
  const float* Wg = (const float*)d_in[1];
  const float* bg = (const float*)d_in[2];
  const float* W1 = (const float*)d_in[3];
  const float* W2 = (const float*)d_in[4];
  const float* W3 = (const float*)d_in[5];
  float* out = (float*)d_out;

  char* ws = (char*)d_ws;
  int* eidx = (int*)ws;
  int* perm = (int*)(ws + 65536);
  int* offs = (int*)(ws + 131072);
  int* cnt = (int*)(ws + 131072 + 128);
  int* scanEx = (int*)(ws + 131072 + 128 + 8192);
  int* tileE = (int*)(ws + 131072 + 128 + 16384);
  int* tileT0 = tileE + MAXTILES + 8;
  ushort* xbf = (ushort*)(ws + 262144);
  ushort* w12b = xbf + (size_t)TT * DD;
  ushort* w3b = w12b + (size_t)EE * 2 * FP * DD;
  ushort* hbf = w3b + (size_t)EE * DD * FP;

  hipMemsetAsync(cnt, 0, EE * NCHUNK * 4, stream);
  gate_conv_kernel<<<TT / 4, 256, 0, stream>>>(x, Wg, bg, eidx, xbf, cnt);
  convw_kernel<<<2048, 256, 0, stream>>>(W1, W2, W3, w12b, w3b);
  scan_kernel<<<1, 512, 0, stream>>>(cnt, scanEx, offs, tileE, tileT0);
  scatter2_kernel<<<NCHUNK / 4, 256, 0, stream>>>(eidx, offs, scanEx, perm);
  ffn1_kernel<<<8 * MAXTILES, 256, 0, stream>>>(xbf, w12b, perm, offs, tileE, tileT0, hbf);
  ffn2_kernel<<<8 * 102, 256, 0, stream>>>(hbf, w3b, perm, offs, tileE, tileT0, out);
}

// Round 11
// 119.282 us; speedup vs baseline: 1.3886x; 1.3886x over previous
//
#include <hip/hip_runtime.h>
#include <hip/hip_bf16.h>
#include <stdint.h>

#define TT 16384
#define DD 768
#define EE 8
#define FF 469
#define FP 512
#define NCHUNK (TT / 64)
#define MAXTILES 136

typedef __attribute__((ext_vector_type(8))) short s16x8;
typedef __attribute__((ext_vector_type(4))) float f32x4;

__device__ __forceinline__ ushort f2bf(float f) {
  uint32_t u = __builtin_bit_cast(uint32_t, f);
  u += 0x7fffu + ((u >> 16) & 1u);
  return (ushort)(u >> 16);
}

__device__ __forceinline__ void gload16(const void* g, void* l) {
  __builtin_amdgcn_global_load_lds((const __attribute__((address_space(1))) unsigned int*)g,
                                   (__attribute__((address_space(3))) unsigned int*)l,
                                   16, 0, 0);
}

// ---------------- fused gating (fp32) + x->bf16 conversion + chunk histogram ----------------
__global__ __launch_bounds__(256) void gate_conv_kernel(
    const float* __restrict__ x, const float* __restrict__ Wg,
    const float* __restrict__ bg, int* __restrict__ eidx,
    ushort* __restrict__ xbf, int* __restrict__ cnt) {
  __shared__ float4 wgs[EE * DD / 4];  // 24 KB
  int tid = threadIdx.x;
  for (int i = tid; i < EE * DD / 4; i += 256) wgs[i] = ((const float4*)Wg)[i];
  __syncthreads();

  int t = blockIdx.x * 4 + (tid >> 6);
  int lane = tid & 63;
  const float4* xr = (const float4*)(x + (size_t)t * DD);
  float4 xv[3];
#pragma unroll
  for (int k = 0; k < 3; ++k) xv[k] = xr[lane + 64 * k];

  float acc[EE];
#pragma unroll
  for (int e = 0; e < EE; ++e) acc[e] = 0.f;
#pragma unroll
  for (int k = 0; k < 3; ++k) {
#pragma unroll
    for (int e = 0; e < EE; ++e) {
      float4 w = wgs[e * 192 + lane + 64 * k];
      acc[e] += xv[k].x * w.x + xv[k].y * w.y + xv[k].z * w.z + xv[k].w * w.w;
    }
  }

  uint2* xd = (uint2*)(xbf + (size_t)t * DD);
#pragma unroll
  for (int k = 0; k < 3; ++k) {
    union { ushort u[4]; uint2 w; } p;
    p.u[0] = f2bf(xv[k].x); p.u[1] = f2bf(xv[k].y);
    p.u[2] = f2bf(xv[k].z); p.u[3] = f2bf(xv[k].w);
    xd[lane + 64 * k] = p.w;
  }

#pragma unroll
  for (int off = 32; off; off >>= 1) {
#pragma unroll
    for (int e = 0; e < EE; ++e) acc[e] += __shfl_down(acc[e], off);
  }
  if (lane == 0) {
    float best = acc[0] + bg[0];
    int bi = 0;
#pragma unroll
    for (int e = 1; e < EE; ++e) {
      float v = acc[e] + bg[e];
      if (v > best) { best = v; bi = e; }
    }
    eidx[t] = bi;
    atomicAdd(&cnt[bi * NCHUNK + (t >> 6)], 1);  // 2048 counters, low contention
  }
}

// ---------------- wave-parallel exclusive scan + flat tile table ----------------
__global__ void scan_kernel(const int* __restrict__ cnt, int* __restrict__ scanEx,
                            int* __restrict__ offs, int* __restrict__ tileE,
                            int* __restrict__ tileT0) {
  int e = threadIdx.x >> 6;
  int lane = threadIdx.x & 63;
  __shared__ int totals[EE];
  int carry = 0;
#pragma unroll
  for (int g = 0; g < NCHUNK / 64; ++g) {
    int v = cnt[e * NCHUNK + g * 64 + lane];
    int s = v;
#pragma unroll
    for (int d = 1; d < 64; d <<= 1) {
      int t = __shfl_up(s, d);
      if (lane >= d) s += t;
    }
    scanEx[e * NCHUNK + g * 64 + lane] = carry + s - v;
    carry += __shfl(s, 63);
  }
  if (lane == 0) totals[e] = carry;
  __syncthreads();
  if (threadIdx.x == 0) {
    int s = 0;
    for (int e2 = 0; e2 < EE; ++e2) { offs[e2] = s; s += totals[e2]; }
    offs[EE] = s;
    int idx = 0;
    for (int e2 = 0; e2 < EE; ++e2) {
      int nt = (totals[e2] + 127) >> 7;
      for (int j = 0; j < nt; ++j) { tileE[idx] = e2; tileT0[idx] = j << 7; ++idx; }
    }
    for (; idx < MAXTILES; ++idx) tileE[idx] = -1;
  }
}

// ---------------- scatter via in-chunk ballot rank ----------------
__global__ void scatter2_kernel(const int* __restrict__ eidx, const int* __restrict__ offs,
                                const int* __restrict__ scanEx, int* __restrict__ perm) {
  int c = blockIdx.x * 4 + (threadIdx.x >> 6);
  int lane = threadIdx.x & 63;
  int t = c * 64 + lane;
  int v = eidx[t];
  unsigned long long mym = 0;
#pragma unroll
  for (int e = 0; e < EE; ++e) {
    unsigned long long me = __ballot(v == e);
    if (v == e) mym = me;
  }
  int rank = __popcll(mym & ((1ULL << lane) - 1ULL));
  perm[offs[v] + scanEx[v * NCHUNK + c] + rank] = t;
}

// ---------------- merged weight conversions: w12b (interleaved) + w3b (padded) ----------------
#define N12 (EE * 2 * FP * (DD / 4))
#define N3  (EE * DD * (FP / 4))
__global__ void convw_kernel(const float* __restrict__ W1, const float* __restrict__ W2,
                             const float* __restrict__ W3, ushort* __restrict__ w12b,
                             ushort* __restrict__ w3b) {
  for (int i = blockIdx.x * blockDim.x + threadIdx.x; i < N12 + N3;
       i += gridDim.x * blockDim.x) {
    if (i < N12) {
      int d4 = i % (DD / 4);
      int er = i / (DD / 4);
      int row = er & 1023;
      int e = er >> 10;
      int f = row >> 1;
      union { ushort u[4]; uint2 w; } p;
      if (f < FF) {
        const float* src = ((row & 1) ? W2 : W1) + ((size_t)e * FF + f) * DD;
        float4 v = ((const float4*)src)[d4];
        p.u[0] = f2bf(v.x); p.u[1] = f2bf(v.y); p.u[2] = f2bf(v.z); p.u[3] = f2bf(v.w);
      } else {
        p.w.x = 0u; p.w.y = 0u;
      }
      ((uint2*)w12b)[i] = p.w;
    } else {
      int j = i - N12;
      int f4 = (j % (FP / 4)) * 4;
      int ed = j / (FP / 4);  // e*DD + d
      union { ushort u[4]; uint2 w; } p;
#pragma unroll
      for (int q = 0; q < 4; ++q) {
        int f = f4 + q;
        p.u[q] = (f < FF) ? f2bf(W3[(size_t)ed * FF + f]) : (ushort)0;
      }
      ((uint2*)w3b)[(size_t)ed * (FP / 4) + (f4 >> 2)] = p.w;
    }
  }
}

// ---------------- grouped GEMM1: 128x256 tile, 8 waves, 3-buf depth-2 counted vmcnt ----------------
__global__ __launch_bounds__(512, 4) void ffn1_kernel(
    const ushort* __restrict__ xbf, const ushort* __restrict__ w12b,
    const int* __restrict__ perm, const int* __restrict__ offs,
    const int* __restrict__ tileE, const int* __restrict__ tileT0,
    ushort* __restrict__ hbf) {
  // grid = 544 = 8*68; XCD-chunked: XCD k owns L in [68k, 68k+68)
  int bid = blockIdx.x;
  int L = (bid & 7) * 68 + (bid >> 3);
  int ti = L >> 2;
  int y = L & 3;
  int e = tileE[ti];
  if (e < 0) return;
  int tile0 = tileT0[ti];
  int gOff = offs[e];
  int Ne = offs[e + 1] - gOff;
  int n0 = y * 256;  // interleaved-col base (0..1023)

  __shared__ __align__(16) short As[3][128 * 32];  // 3 x 8 KB
  __shared__ __align__(16) short Bs[3][256 * 32];  // 3 x 16 KB

  int tid = threadIdx.x;
  int w = tid >> 6, lane = tid & 63;
  int lr = lane >> 2, lg = lane & 3;

  // A staging: wave w stages rows [w*16, w*16+16): 1 gload
  int ar = w * 16 + lr;
  int ag = lg ^ ((ar >> 1) & 3);
  int last = gOff + Ne - 1;
  int tok = perm[min(gOff + tile0 + ar, last)];
  const ushort* asrc = xbf + (size_t)tok * DD + ag * 8;
  int adst = (w * 16) * 32;

  // B staging: wave w stages rows [w*32, w*32+32): 2 gloads
  int br0 = w * 32 + lr, br1 = br0 + 16;
  int bg0 = lg ^ ((br0 >> 1) & 3);
  int bg1 = lg ^ ((br1 >> 1) & 3);
  const ushort* bsrc0 = w12b + ((size_t)(e << 10) + n0 + br0) * DD + bg0 * 8;
  const ushort* bsrc1 = w12b + ((size_t)(e << 10) + n0 + br1) * DD + bg1 * 8;
  int bdst0 = (w * 32) * 32;
  int bdst1 = bdst0 + 16 * 32;

  // compute: wave (wr, wc) owns rows wr*64..+64, cols wc*64..+64 (of 128x256)
  int wr = w >> 2, wc = w & 3;
  int lrow = lane & 15, kh = lane >> 4;
  int aoff[4], boff[4];
#pragma unroll
  for (int m = 0; m < 4; ++m) {
    int ra = wr * 64 + m * 16 + lrow;
    aoff[m] = ra * 32 + (kh ^ ((ra >> 1) & 3)) * 8;
    int rb = wc * 64 + m * 16 + lrow;
    boff[m] = rb * 32 + (kh ^ ((rb >> 1) & 3)) * 8;
  }

  f32x4 acc[4][4];
  f32x4 zero = {0.f, 0.f, 0.f, 0.f};
#pragma unroll
  for (int m = 0; m < 4; ++m)
#pragma unroll
    for (int n = 0; n < 4; ++n) acc[m][n] = zero;

  // prologue: T0 -> buf0, T1 -> buf1 (6 outstanding/wave)
#pragma unroll
  for (int t = 0; t < 2; ++t) {
    int k = t * 32;
    gload16(asrc + k, &As[t][adst]);
    gload16(bsrc0 + k, &Bs[t][bdst0]);
    gload16(bsrc1 + k, &Bs[t][bdst1]);
  }

  const int NT = DD / 32;  // 24
#pragma unroll
  for (int t = 0; t < NT; ++t) {
    const int cur = t % 3;
    if (t < NT - 1) asm volatile("s_waitcnt vmcnt(3)" ::: "memory");  // T(t+1)'s 3 in flight
    else            asm volatile("s_waitcnt vmcnt(0)" ::: "memory");
    __builtin_amdgcn_s_barrier();
    __builtin_amdgcn_sched_barrier(0);
    if (t + 2 < NT) {
      const int nb = (t + 2) % 3;
      int k = (t + 2) * 32;
      gload16(asrc + k, &As[nb][adst]);
      gload16(bsrc0 + k, &Bs[nb][bdst0]);
      gload16(bsrc1 + k, &Bs[nb][bdst1]);
    }
    s16x8 af[4], bfr[4];
#pragma unroll
    for (int m = 0; m < 4; ++m) af[m] = *(const s16x8*)&As[cur][aoff[m]];
#pragma unroll
    for (int n = 0; n < 4; ++n) bfr[n] = *(const s16x8*)&Bs[cur][boff[n]];
    __builtin_amdgcn_s_setprio(1);
#pragma unroll
    for (int m = 0; m < 4; ++m)
#pragma unroll
      for (int n = 0; n < 4; ++n)
        acc[m][n] = __builtin_amdgcn_mfma_f32_16x16x32_bf16(af[m], bfr[n], acc[m][n], 0, 0, 0);
    __builtin_amdgcn_s_setprio(0);
  }

  // epilogue: interleaved cols 2f,2f+1 = u_f,v_f in adjacent lanes (R6-proven)
#pragma unroll
  for (int m = 0; m < 4; ++m) {
    int rbase = tile0 + wr * 64 + m * 16 + kh * 4;
#pragma unroll
    for (int n = 0; n < 4; ++n) {
      int f = (n0 + wc * 64 + n * 16 + lrow) >> 1;
#pragma unroll
      for (int r = 0; r < 4; ++r) {
        float val = acc[m][n][r];
        float par = __shfl_xor(val, 1);
        float u = (lane & 1) ? par : val;
        float vv = (lane & 1) ? val : par;
        float h = (u / (1.f + __expf(-u))) * vv;
        int gr = rbase + r;
        if (!(lane & 1) && gr < Ne)
          hbf[(size_t)(gOff + gr) * FP + f] = f2bf(h);
      }
    }
  }
}

// ---------------- grouped GEMM2: 128x256 tile, 8 waves, 3-buf depth-2 counted vmcnt ----------------
__global__ __launch_bounds__(512, 4) void ffn2_kernel(
    const ushort* __restrict__ hbf, const ushort* __restrict__ w3b,
    const int* __restrict__ perm, const int* __restrict__ offs,
    const int* __restrict__ tileE, const int* __restrict__ tileT0,
    float* __restrict__ out) {
  // grid = 408 = 8*51; XCD k owns L in [51k, 51k+51)
  int bid = blockIdx.x;
  int L = (bid & 7) * 51 + (bid >> 3);
  int ti = L / 3;
  int y = L % 3;
  int e = tileE[ti];
  if (e < 0) return;
  int tile0 = tileT0[ti];
  int gOff = offs[e];
  int Ne = offs[e + 1] - gOff;
  int d0 = y * 256;

  __shared__ __align__(16) short As[3][128 * 32];
  __shared__ __align__(16) short Bs[3][256 * 32];

  int tid = threadIdx.x;
  int w = tid >> 6, lane = tid & 63;
  int lr = lane >> 2, lg = lane & 3;

  int ar = w * 16 + lr;
  int ag = lg ^ ((ar >> 1) & 3);
  int last = gOff + Ne - 1;
  const ushort* asrc = hbf + (size_t)min(gOff + tile0 + ar, last) * FP + ag * 8;
  int adst = (w * 16) * 32;

  int br0 = w * 32 + lr, br1 = br0 + 16;
  int bg0 = lg ^ ((br0 >> 1) & 3);
  int bg1 = lg ^ ((br1 >> 1) & 3);
  const ushort* bsrc0 = w3b + ((size_t)e * DD + d0 + br0) * FP + bg0 * 8;
  const ushort* bsrc1 = w3b + ((size_t)e * DD + d0 + br1) * FP + bg1 * 8;
  int bdst0 = (w * 32) * 32;
  int bdst1 = bdst0 + 16 * 32;

  int wr = w >> 2, wc = w & 3;
  int lrow = lane & 15, kh = lane >> 4;
  int aoff[4], boff[4];
#pragma unroll
  for (int m = 0; m < 4; ++m) {
    int ra = wr * 64 + m * 16 + lrow;
    aoff[m] = ra * 32 + (kh ^ ((ra >> 1) & 3)) * 8;
    int rb = wc * 64 + m * 16 + lrow;
    boff[m] = rb * 32 + (kh ^ ((rb >> 1) & 3)) * 8;
  }

  f32x4 acc[4][4];
  f32x4 zero = {0.f, 0.f, 0.f, 0.f};
#pragma unroll
  for (int m = 0; m < 4; ++m)
#pragma unroll
    for (int n = 0; n < 4; ++n) acc[m][n] = zero;

#pragma unroll
  for (int t = 0; t < 2; ++t) {
    int k = t * 32;
    gload16(asrc + k, &As[t][adst]);
    gload16(bsrc0 + k, &Bs[t][bdst0]);
    gload16(bsrc1 + k, &Bs[t][bdst1]);
  }

  const int NT = FP / 32;  // 16
#pragma unroll
  for (int t = 0; t < NT; ++t) {
    const int cur = t % 3;
    if (t < NT - 1) asm volatile("s_waitcnt vmcnt(3)" ::: "memory");
    else            asm volatile("s_waitcnt vmcnt(0)" ::: "memory");
    __builtin_amdgcn_s_barrier();
    __builtin_amdgcn_sched_barrier(0);
    if (t + 2 < NT) {
      const int nb = (t + 2) % 3;
      int k = (t + 2) * 32;
      gload16(asrc + k, &As[nb][adst]);
      gload16(bsrc0 + k, &Bs[nb][bdst0]);
      gload16(bsrc1 + k, &Bs[nb][bdst1]);
    }
    s16x8 af[4], bfr[4];
#pragma unroll
    for (int m = 0; m < 4; ++m) af[m] = *(const s16x8*)&As[cur][aoff[m]];
#pragma unroll
    for (int n = 0; n < 4; ++n) bfr[n] = *(const s16x8*)&Bs[cur][boff[n]];
    __builtin_amdgcn_s_setprio(1);
#pragma unroll
    for (int m = 0; m < 4; ++m)
#pragma unroll
      for (int n = 0; n < 4; ++n)
        acc[m][n] = __builtin_amdgcn_mfma_f32_16x16x32_bf16(af[m], bfr[n], acc[m][n], 0, 0, 0);
    __builtin_amdgcn_s_setprio(0);
  }

#pragma unroll
  for (int m = 0; m < 4; ++m) {
#pragma unroll
    for (int r = 0; r < 4; ++r) {
      int gr = tile0 + wr * 64 + m * 16 + kh * 4 + r;
      if (gr < Ne) {
        int t = perm[gOff + gr];
        float* orow = out + (size_t)t * DD + d0 + wc * 64;
#pragma unroll
        for (int n = 0; n < 4; ++n) orow[n * 16 + lrow] = acc[m][n][r];
      }
    }
  }
}

extern "C" void kernel_launch(void* const* d_in, const int* in_sizes, int n_in,
                              void* d_out, int out_size, void* d_ws, size_t ws_size,
                              hipStream_t stream) {
  const float* x = (const float*)d_in[0];
  const float* Wg = (const float*)d_in[1];
  const float* bg = (const float*)d_in[2];
  const float* W1 = (const float*)d_in[3];
  const float* W2 = (const float*)d_in[4];
  const float* W3 = (const float*)d_in[5];
  float* out = (float*)d_out;

  char* ws = (char*)d_ws;
  int* eidx = (int*)ws;
  int* perm = (int*)(ws + 65536);
  int* offs = (int*)(ws + 131072);
  int* cnt = (int*)(ws + 131072 + 128);
  int* scanEx = (int*)(ws + 131072 + 128 + 8192);
  int* tileE = (int*)(ws + 131072 + 128 + 16384);
  int* tileT0 = tileE + MAXTILES + 8;
  ushort* xbf = (ushort*)(ws + 262144);
  ushort* w12b = xbf + (size_t)TT * DD;
  ushort* w3b = w12b + (size_t)EE * 2 * FP * DD;
  ushort* hbf = w3b + (size_t)EE * DD * FP;

  hipMemsetAsync(cnt, 0, EE * NCHUNK * 4, stream);
  gate_conv_kernel<<<TT / 4, 256, 0, stream>>>(x, Wg, bg, eidx, xbf, cnt);
  convw_kernel<<<2048, 256, 0, stream>>>(W1, W2, W3, w12b, w3b);
  scan_kernel<<<1, 512, 0, stream>>>(cnt, scanEx, offs, tileE, tileT0);
  scatter2_kernel<<<NCHUNK / 4, 256, 0, stream>>>(eidx, offs, scanEx, perm);
  ffn1_kernel<<<8 * 68, 512, 0, stream>>>(xbf, w12b, perm, offs, tileE, tileT0, hbf);
  ffn2_kernel<<<8 * 51, 512, 0, stream>>>(hbf, w3b, perm, offs, tileE, tileT0, out);
}